// Round 5
// baseline (405.911 us; speedup 1.0000x reference)
//
#include <hip/hip_runtime.h>
#include <hip/hip_bf16.h>
#include <math.h>

// IntentionHeads: per-token 2-head MLP with head selection.
//   repr3 [32,2048,512] f32 -> X [65536,512]          (f32 on device)
//   agent_type_ids [32,2048]                           (int32 on device per
//                                                       harness contract)
//   layer1: H = GELU(X @ W1^T + b1)   W1 [256,512] f32
//   layer2: logits = H @ W2^T + b2    W2 [6,256]/[2,256] f32
//   out: FLOAT32 (reference output dtype!):
//        logits [65536,6] ++ v_mask [65536] ++ p_mask [65536]  (masks 1.0/0.0)
//
// R3==R4 identical absmax proved the MFMA path == exact f32 path; the prior
// failures were d_out dtype (bf16 written into a float* buffer). This is the
// round-2 MFMA kernel with f32 output writes and int32 ids.
//
// Grid = (tokens/64) * 2 heads; block = 256 threads (4 waves), wave tile
// 64 tokens x 64 hidden, MFMA 16x16x32 bf16, fragments loaded from global f32
// and converted in-register (v_cvt_pk_bf16_f32).

#define TOKENS 65536
#define DIM    512
#define HID    256
#define LDS_STRIDE 264   // 256 + 8 bf16 pad

using short8 = __attribute__((ext_vector_type(8))) short;  // 8 x bf16
using f32x4  = __attribute__((ext_vector_type(4))) float;

__device__ __forceinline__ short bfbits(float x) {
    __hip_bfloat16 h = __float2bfloat16(x);
    union { __hip_bfloat16 h; short s; } u; u.h = h;
    return u.s;
}

// load 8 consecutive f32 and convert to a bf16x8 fragment
__device__ __forceinline__ short8 load_cvt8(const float* __restrict__ p) {
    f32x4 a = *(const f32x4*)p;
    f32x4 b = *(const f32x4*)(p + 4);
    short8 r;
    r[0] = bfbits(a[0]); r[1] = bfbits(a[1]); r[2] = bfbits(a[2]); r[3] = bfbits(a[3]);
    r[4] = bfbits(b[0]); r[5] = bfbits(b[1]); r[6] = bfbits(b[2]); r[7] = bfbits(b[3]);
    return r;
}

__device__ __forceinline__ float gelu_exact(float x) {
    // exact (erf) GELU, matches jax.nn.gelu(approximate=False)
    return 0.5f * x * (1.0f + erff(x * 0.7071067811865475f));
}

__global__ __launch_bounds__(256, 2)
void intention_heads_kernel(const float* __restrict__ X,
                            const int* __restrict__ ids,    // int32 on device
                            const float* __restrict__ vW1,
                            const float* __restrict__ vb1,
                            const float* __restrict__ vW2,
                            const float* __restrict__ vb2,
                            const float* __restrict__ pW1,
                            const float* __restrict__ pb1,
                            const float* __restrict__ pW2,
                            const float* __restrict__ pb2,
                            float* __restrict__ out)        // FLOAT32 output
{
    __shared__ __hip_bfloat16 hlds[64 * LDS_STRIDE];   // 33.0 KiB

    const int bx   = blockIdx.x;
    const int head = bx & 1;           // 0 = vehicle, 1 = pedestrian
    const int row0 = (bx >> 1) * 64;   // first token of this tile

    const int tid  = threadIdx.x;
    const int wave = tid >> 6;         // 0..3 -> hidden cols [64w, 64w+64)
    const int lane = tid & 63;
    const int quad = lane >> 4;        // 0..3
    const int l16  = lane & 15;
    const int wcol = wave * 64;

    const float* W1 = head ? pW1 : vW1;
    const float* b1 = head ? pb1 : vb1;

    // ---------------- layer 1 GEMM: 64 tokens x 256 hidden, K = 512 -------
    f32x4 acc[4][4];
    #pragma unroll
    for (int i = 0; i < 4; ++i)
        #pragma unroll
        for (int j = 0; j < 4; ++j)
            acc[i][j] = (f32x4){0.f, 0.f, 0.f, 0.f};

    // A-frag: lane holds X[row0 + i*16 + l16][k0 + quad*8 .. +8]
    // B-frag: lane holds W1[wcol + j*16 + l16][k0 + quad*8 .. +8]
    long aoff[4], boff[4];
    #pragma unroll
    for (int i = 0; i < 4; ++i)
        aoff[i] = (long)(row0 + i * 16 + l16) * DIM + quad * 8;
    #pragma unroll
    for (int j = 0; j < 4; ++j)
        boff[j] = (long)(wcol + j * 16 + l16) * DIM + quad * 8;

    for (int k0 = 0; k0 < DIM; k0 += 32) {
        short8 a[4], b[4];
        #pragma unroll
        for (int i = 0; i < 4; ++i)
            a[i] = load_cvt8(X + aoff[i] + k0);
        #pragma unroll
        for (int j = 0; j < 4; ++j)
            b[j] = load_cvt8(W1 + boff[j] + k0);
        #pragma unroll
        for (int i = 0; i < 4; ++i)
            #pragma unroll
            for (int j = 0; j < 4; ++j)
                acc[i][j] = __builtin_amdgcn_mfma_f32_16x16x32_bf16(a[i], b[j], acc[i][j], 0, 0, 0);
    }

    // ------------- bias + GELU, stage H tile into LDS (bf16) --------------
    // C/D layout: col = l16, row = quad*4 + r  (within each 16x16 tile)
    float b1v[4];
    #pragma unroll
    for (int j = 0; j < 4; ++j)
        b1v[j] = b1[wcol + j * 16 + l16];

    #pragma unroll
    for (int i = 0; i < 4; ++i) {
        #pragma unroll
        for (int j = 0; j < 4; ++j) {
            const int col = wcol + j * 16 + l16;
            #pragma unroll
            for (int r = 0; r < 4; ++r) {
                const int row = i * 16 + quad * 4 + r;
                float v = acc[i][j][r] + b1v[j];
                hlds[row * LDS_STRIDE + col] = __float2bfloat16(gelu_exact(v));
            }
        }
    }
    __syncthreads();

    // ---------------- layer 2: H[64x256] @ W2^T, MFMA, N padded to 16 -----
    const float* W2 = head ? pW2 : vW2;
    const float* b2 = head ? pb2 : vb2;
    const int nOut = head ? 2 : 6;

    f32x4 acc2 = (f32x4){0.f, 0.f, 0.f, 0.f};
    const int tokb = wave * 16;  // this wave's 16-token sub-tile
    const short* hbase = (const short*)&hlds[(tokb + l16) * LDS_STRIDE + quad * 8];
    #pragma unroll
    for (int k0 = 0; k0 < HID; k0 += 32) {
        short8 af = *(const short8*)(hbase + k0);
        short8 bfrag = (short8){0, 0, 0, 0, 0, 0, 0, 0};
        if (l16 < nOut)
            bfrag = load_cvt8(W2 + l16 * HID + k0 + quad * 8);
        acc2 = __builtin_amdgcn_mfma_f32_16x16x32_bf16(af, bfrag, acc2, 0, 0, 0);
    }

    // ---------------- masked epilogue (f32 writes) ------------------------
    // acc2: token = row0 + tokb + quad*4 + r, output idx o = l16
    const float b2v = (l16 < nOut) ? b2[l16] : 0.0f;

    #pragma unroll
    for (int r = 0; r < 4; ++r) {
        const int t = row0 + tokb + quad * 4 + r;
        const int type = ids[t];
        if (head == 0) {
            if (l16 == 0) {
                // vehicle-head block owns the mask outputs
                out[TOKENS * 6 + t] = (type == 1) ? 1.0f : 0.0f;
                out[TOKENS * 7 + t] = (type == 2) ? 1.0f : 0.0f;
            }
            if (l16 < 6) {
                if (type == 1)
                    out[t * 6 + l16] = acc2[r] + b2v;
                else if (type != 2)
                    out[t * 6 + l16] = 0.0f;        // types 0,3 -> zeros
                // type==2 written by the pedestrian-head block
            }
        } else {
            if (l16 < 6 && type == 2)
                out[t * 6 + l16] = (l16 < 2) ? (acc2[r] + b2v) : 0.0f;
        }
    }
}

extern "C" void kernel_launch(void* const* d_in, const int* in_sizes, int n_in,
                              void* d_out, int out_size, void* d_ws, size_t ws_size,
                              hipStream_t stream) {
    (void)n_in; (void)out_size; (void)d_ws; (void)ws_size;
    const float* X   = (const float*)d_in[0];
    const int*   ids = (const int*)d_in[1];     // integer -> const int*
    const float* vW1 = (const float*)d_in[2];
    const float* vb1 = (const float*)d_in[3];
    const float* vW2 = (const float*)d_in[4];
    const float* vb2 = (const float*)d_in[5];
    const float* pW1 = (const float*)d_in[6];
    const float* pb1 = (const float*)d_in[7];
    const float* pW2 = (const float*)d_in[8];
    const float* pb2 = (const float*)d_in[9];
    float* out = (float*)d_out;                 // float32 output buffer

    const int tokens = in_sizes[1];            // 65536
    const int grid   = (tokens / 64) * 2;      // token-tile x head

    hipLaunchKernelGGL(intention_heads_kernel, dim3(grid), dim3(256), 0, stream,
                       X, ids, vW1, vb1, vW2, vb2, pW1, pb1, pW2, pb2, out);
}

// Round 6
// 284.440 us; speedup vs baseline: 1.4271x; 1.4271x over previous
//
#include <hip/hip_runtime.h>
#include <hip/hip_bf16.h>
#include <math.h>

// IntentionHeads: per-token 2-head MLP with head selection. (f32 in, f32 out)
//   X [65536,512] f32; layer1 H=GELU(X@W1^T+b1) (W1 [256,512]);
//   layer2 logits=H@W2^T+b2 (W2 [6,256]/[2,256]);
//   out f32: logits[65536,6] ++ v_mask[65536] ++ p_mask[65536]
//
// R5 passed at 262.8us: VALU-bound on software f32->bf16 (55us) + unhidden
// L2 latency (no staging/pipelining). This round:
//  - LDS-staged K-loop: block converts A(64x32)/B(256x32) tiles to bf16 ONCE
//    (4-op bit-trick RNE), waves read frags via ds_read_b128 (stride 40 pad).
//  - Register prefetch of next K-tile issued before the MFMAs.
//  - LDS stage (25.6KB) unioned with H tile (33.8KB) -> 4 blocks/CU by LDS.

#define TOKENS 65536
#define DIM    512
#define HID    256
#define BK     32
#define ASTR   40    // staged tile row stride in bf16 (32 + 8 pad)
#define HSTR   264   // H tile row stride in bf16

using short8 = __attribute__((ext_vector_type(8))) short;  // 8 x bf16
using f32x4  = __attribute__((ext_vector_type(4))) float;

// round-to-nearest-even f32->bf16, two at a time, packed into a uint
__device__ __forceinline__ unsigned int pkrne(float a, float b) {
    unsigned int ua = __float_as_uint(a);
    unsigned int ub = __float_as_uint(b);
    ua += 0x7FFFu + ((ua >> 16) & 1u);
    ub += 0x7FFFu + ((ub >> 16) & 1u);
    return (ub & 0xFFFF0000u) | (ua >> 16);
}

__device__ __forceinline__ uint2 cvt4(f32x4 v) {
    return make_uint2(pkrne(v[0], v[1]), pkrne(v[2], v[3]));
}

// 8 consecutive f32 -> bf16x8 fragment (for layer-2 W2 loads)
__device__ __forceinline__ short8 cvt8(const float* __restrict__ p) {
    f32x4 a = *(const f32x4*)p;
    f32x4 b = *(const f32x4*)(p + 4);
    union { unsigned int u[4]; short8 s; } r;
    r.u[0] = pkrne(a[0], a[1]);
    r.u[1] = pkrne(a[2], a[3]);
    r.u[2] = pkrne(b[0], b[1]);
    r.u[3] = pkrne(b[2], b[3]);
    return r.s;
}

__device__ __forceinline__ float gelu_exact(float x) {
    // exact (erf) GELU, matches jax.nn.gelu(approximate=False)
    return 0.5f * x * (1.0f + erff(x * 0.7071067811865475f));
}

__global__ __launch_bounds__(256, 2)
void intention_heads_kernel(const float* __restrict__ X,
                            const int* __restrict__ ids,
                            const float* __restrict__ vW1,
                            const float* __restrict__ vb1,
                            const float* __restrict__ vW2,
                            const float* __restrict__ vb2,
                            const float* __restrict__ pW1,
                            const float* __restrict__ pb1,
                            const float* __restrict__ pW2,
                            const float* __restrict__ pb2,
                            float* __restrict__ out)
{
    // LDS union: staging (At 64x40 + Bt 256x40 bf16 = 25.6 KB) then H (64x264
    // bf16 = 33.8 KB). 33792 B total -> 4 blocks/CU by LDS.
    __shared__ __align__(16) unsigned char smem[64 * HSTR * 2];
    __hip_bfloat16* At = (__hip_bfloat16*)smem;                    // [64][ASTR]
    __hip_bfloat16* Bt = (__hip_bfloat16*)(smem + 64 * ASTR * 2);  // [256][ASTR]
    __hip_bfloat16* H  = (__hip_bfloat16*)smem;                    // [64][HSTR]

    const int bx   = blockIdx.x;
    const int head = bx & 1;           // 0 = vehicle, 1 = pedestrian
    const int row0 = (bx >> 1) * 64;   // first token of this tile

    const int tid  = threadIdx.x;
    const int wave = tid >> 6;         // 0..3 -> hidden cols [64w, 64w+64)
    const int lane = tid & 63;
    const int quad = lane >> 4;        // 0..3
    const int l16  = lane & 15;
    const int wcol = wave * 64;

    const float* W1 = head ? pW1 : vW1;
    const float* b1 = head ? pb1 : vb1;

    // staging decomposition: thread owns f32x4 chunks at column q*4, rows
    //   A: r0t, r0t+32   B: r0t + 32*e (e=0..7)
    const int q   = tid & 7;
    const int r0t = tid >> 3;          // 0..31
    const float* Xs  = X  + (long)(row0 + r0t) * DIM + q * 4;
    const float* W1s = W1 + (long)r0t * DIM + q * 4;

    f32x4 pa[2], pb[8];
    #define LOADTILE(k0)                                              \
        do {                                                          \
            pa[0] = *(const f32x4*)(Xs + (k0));                       \
            pa[1] = *(const f32x4*)(Xs + 32 * DIM + (k0));            \
            _Pragma("unroll")                                         \
            for (int e = 0; e < 8; ++e)                               \
                pb[e] = *(const f32x4*)(W1s + e * 32 * DIM + (k0));   \
        } while (0)

    f32x4 acc[4][4];
    #pragma unroll
    for (int i = 0; i < 4; ++i)
        #pragma unroll
        for (int j = 0; j < 4; ++j)
            acc[i][j] = (f32x4){0.f, 0.f, 0.f, 0.f};

    LOADTILE(0);

    for (int it = 0; it < DIM / BK; ++it) {
        // convert staged registers -> LDS bf16 tiles
        *(uint2*)&At[(r0t)      * ASTR + q * 4] = cvt4(pa[0]);
        *(uint2*)&At[(r0t + 32) * ASTR + q * 4] = cvt4(pa[1]);
        #pragma unroll
        for (int e = 0; e < 8; ++e)
            *(uint2*)&Bt[(r0t + 32 * e) * ASTR + q * 4] = cvt4(pb[e]);
        __syncthreads();

        // fragment reads (A: 16 tokens x 32k per frag; B: 16 hid x 32k)
        short8 af[4], bf_[4];
        #pragma unroll
        for (int i = 0; i < 4; ++i)
            af[i] = *(const short8*)&At[(i * 16 + l16) * ASTR + quad * 8];
        #pragma unroll
        for (int j = 0; j < 4; ++j)
            bf_[j] = *(const short8*)&Bt[(wcol + j * 16 + l16) * ASTR + quad * 8];

        // prefetch next K-tile while MFMAs run
        if (it + 1 < DIM / BK)
            LOADTILE((it + 1) * BK);

        #pragma unroll
        for (int i = 0; i < 4; ++i)
            #pragma unroll
            for (int j = 0; j < 4; ++j)
                acc[i][j] = __builtin_amdgcn_mfma_f32_16x16x32_bf16(af[i], bf_[j], acc[i][j], 0, 0, 0);
        __syncthreads();   // frag reads done before next iter's writes / H
    }

    // ------------- bias + GELU, stage H tile into LDS (bf16) --------------
    // C/D layout: col = l16, row = quad*4 + r (within each 16x16 tile)
    float b1v[4];
    #pragma unroll
    for (int j = 0; j < 4; ++j)
        b1v[j] = b1[wcol + j * 16 + l16];

    #pragma unroll
    for (int i = 0; i < 4; ++i) {
        #pragma unroll
        for (int j = 0; j < 4; ++j) {
            const int col = wcol + j * 16 + l16;
            #pragma unroll
            for (int r = 0; r < 4; ++r) {
                const int row = i * 16 + quad * 4 + r;
                float v = acc[i][j][r] + b1v[j];
                union { unsigned int u; struct { short lo, hi; } s; } t;
                t.u = pkrne(v == v ? gelu_exact(v) : 0.f, 0.f);  // RNE bf16
                H[row * HSTR + col] = *(__hip_bfloat16*)&t.s.lo;
            }
        }
    }
    __syncthreads();

    // ---------------- layer 2: H[64x256] @ W2^T, MFMA, N padded to 16 -----
    const float* W2 = head ? pW2 : vW2;
    const float* b2 = head ? pb2 : vb2;
    const int nOut = head ? 2 : 6;

    f32x4 acc2 = (f32x4){0.f, 0.f, 0.f, 0.f};
    const int tokb = wave * 16;  // this wave's 16-token sub-tile
    const short* hbase = (const short*)&H[(tokb + l16) * HSTR + quad * 8];
    #pragma unroll
    for (int k0 = 0; k0 < HID; k0 += 32) {
        short8 af = *(const short8*)(hbase + k0);
        short8 bfrag = (short8){0, 0, 0, 0, 0, 0, 0, 0};
        if (l16 < nOut)
            bfrag = cvt8(W2 + l16 * HID + k0 + quad * 8);
        acc2 = __builtin_amdgcn_mfma_f32_16x16x32_bf16(af, bfrag, acc2, 0, 0, 0);
    }

    // ---------------- masked epilogue (f32 writes) ------------------------
    const float b2v = (l16 < nOut) ? b2[l16] : 0.0f;

    #pragma unroll
    for (int r = 0; r < 4; ++r) {
        const int t = row0 + tokb + quad * 4 + r;
        const int type = ids[t];
        if (head == 0) {
            if (l16 == 0) {
                out[TOKENS * 6 + t] = (type == 1) ? 1.0f : 0.0f;
                out[TOKENS * 7 + t] = (type == 2) ? 1.0f : 0.0f;
            }
            if (l16 < 6) {
                if (type == 1)
                    out[t * 6 + l16] = acc2[r] + b2v;
                else if (type != 2)
                    out[t * 6 + l16] = 0.0f;        // types 0,3 -> zeros
                // type==2 written by the pedestrian-head block
            }
        } else {
            if (l16 < 6 && type == 2)
                out[t * 6 + l16] = (l16 < 2) ? (acc2[r] + b2v) : 0.0f;
        }
    }
}

extern "C" void kernel_launch(void* const* d_in, const int* in_sizes, int n_in,
                              void* d_out, int out_size, void* d_ws, size_t ws_size,
                              hipStream_t stream) {
    (void)n_in; (void)out_size; (void)d_ws; (void)ws_size;
    const float* X   = (const float*)d_in[0];
    const int*   ids = (const int*)d_in[1];
    const float* vW1 = (const float*)d_in[2];
    const float* vb1 = (const float*)d_in[3];
    const float* vW2 = (const float*)d_in[4];
    const float* vb2 = (const float*)d_in[5];
    const float* pW1 = (const float*)d_in[6];
    const float* pb1 = (const float*)d_in[7];
    const float* pW2 = (const float*)d_in[8];
    const float* pb2 = (const float*)d_in[9];
    float* out = (float*)d_out;

    const int tokens = in_sizes[1];            // 65536
    const int grid   = (tokens / 64) * 2;      // token-tile x head

    hipLaunchKernelGGL(intention_heads_kernel, dim3(grid), dim3(256), 0, stream,
                       X, ids, vW1, vb1, vW2, vb2, pW1, pb1, pW2, pb2, out);
}